// Round 15
// baseline (756.136 us; speedup 1.0000x reference)
//
#include <hip/hip_runtime.h>

typedef __attribute__((ext_vector_type(8))) short bf16x8;
typedef __attribute__((ext_vector_type(4))) short bf16x4;
typedef __attribute__((ext_vector_type(4))) float f32x4;

#define MFMA(a, b, c) __builtin_amdgcn_mfma_f32_16x16x32_bf16((a), (b), (c), 0, 0, 0)

__device__ __forceinline__ unsigned short f2bf(float f) {
  unsigned int x = __float_as_uint(f);
  return (unsigned short)((x + 0x7fffu + ((x >> 16) & 1u)) >> 16);
}
__device__ __forceinline__ float bf2f(unsigned short u) {
  return __uint_as_float(((unsigned int)u) << 16);
}
__device__ __forceinline__ unsigned int cvtpk(float lo, float hi) {
  unsigned int r;
  asm("v_cvt_pk_bf16_f32 %0, %1, %2" : "=v"(r) : "v"(lo), "v"(hi));
  return r;
}

constexpr int SEQ = 2048;
constexpr int NH = 8;
constexpr int DH = 128;
constexpr int DIM = 1024;
constexpr float SCALE = 0.08838834764831845f; // 1/sqrt(128)

// ---------------------------------------------------------------------------
// K1: qkv = x @ qkv_proj^T  (M=4096, N=3072, K=1024), fused RoPE epilogue.
// (round-4 form, best measured)
// ---------------------------------------------------------------------------
__global__ __launch_bounds__(256) void k_qkv_rope(
    const float* __restrict__ x, const float* __restrict__ wqkv,
    const float* __restrict__ cosT, const float* __restrict__ sinT,
    unsigned short* __restrict__ q, unsigned short* __restrict__ k,
    unsigned short* __restrict__ vT)
{
  __shared__ __align__(16) unsigned short As[128][40];
  __shared__ __align__(16) unsigned short Bs[128][40];
  const int tid = threadIdx.x;
  const int wave = tid >> 6, lane = tid & 63;
  const int fr = lane & 15, fq = lane >> 4;
  const int fk = fq * 8;
  const int wr = (wave >> 1) * 64, wc = (wave & 1) * 64;
  const int m0 = blockIdx.x * 128, n0 = blockIdx.y * 128;

  f32x4 zero4 = {0.f, 0.f, 0.f, 0.f};
  f32x4 acc[4][4];
  for (int i = 0; i < 4; ++i)
    for (int j = 0; j < 4; ++j) acc[i][j] = zero4;

  for (int kt = 0; kt < 32; ++kt) {
    const int k0 = kt * 32;
    __syncthreads();
#pragma unroll
    for (int j = 0; j < 4; ++j) {
      int f = j * 256 + tid;
      int row = f >> 3, c4 = (f & 7) * 4;
      f32x4 va = *(const f32x4*)(x + (m0 + row) * 1024 + k0 + c4);
      f32x4 vb = *(const f32x4*)(wqkv + (n0 + row) * 1024 + k0 + c4);
      uint2 ua, ub;
      ua.x = cvtpk(va[0], va[1]); ua.y = cvtpk(va[2], va[3]);
      ub.x = cvtpk(vb[0], vb[1]); ub.y = cvtpk(vb[2], vb[3]);
      *(uint2*)&As[row][c4] = ua;
      *(uint2*)&Bs[row][c4] = ub;
    }
    __syncthreads();
    bf16x8 af[4], bfr[4];
#pragma unroll
    for (int mi = 0; mi < 4; ++mi) af[mi] = *(const bf16x8*)&As[wr + mi * 16 + fr][fk];
#pragma unroll
    for (int ni = 0; ni < 4; ++ni) bfr[ni] = *(const bf16x8*)&Bs[wc + ni * 16 + fr][fk];
#pragma unroll
    for (int mi = 0; mi < 4; ++mi)
#pragma unroll
      for (int ni = 0; ni < 4; ++ni)
        acc[mi][ni] = MFMA(af[mi], bfr[ni], acc[mi][ni]);
  }

#pragma unroll
  for (int mi = 0; mi < 4; ++mi)
#pragma unroll
    for (int ni = 0; ni < 4; ++ni)
#pragma unroll
      for (int r = 0; r < 4; ++r) {
        float val = acc[mi][ni][r];
        float other = __shfl_xor(val, 1, 64);
        int m = m0 + wr + mi * 16 + fq * 4 + r;
        int n = n0 + wc + ni * 16 + fr;
        int a = n >> 10, feat = n & 1023;
        int hh = feat >> 7, dh = feat & 127;
        int bi = m >> 11, t = m & 2047;
        if (a == 2) {
          vT[((bi * NH + hh) * DH + dh) * SEQ + t] = f2bf(val);
        } else {
          float c = cosT[t * 64 + (dh >> 1)];
          float s = sinT[t * 64 + (dh >> 1)];
          float o = ((dh & 1) == 0) ? (val * c - other * s) : (other * s + val * c);
          unsigned short* dst = (a == 0) ? q : k;
          dst[((bi * NH + hh) * SEQ + t) * DH + dh] = f2bf(o);
        }
      }
}

// ---------------------------------------------------------------------------
// K2: causal attention, SINGLE pass. Swapped QK^T (S^T per lane). Stores
// unnormalized bf16 P~ into the attn buffer's own memory (bf16 mirror of
// row i at byte 4*rowbase + 2*col), accumulates rowsum + PV; epilogue
// normalizes + expands bf16->f32 in place (descending quarters + vmcnt
// fences make the 2x expansion race-free).
// ---------------------------------------------------------------------------
__global__ __launch_bounds__(256) void k_attn(
    const unsigned short* __restrict__ q, const unsigned short* __restrict__ k,
    const unsigned short* __restrict__ vT,
    float* __restrict__ attn, unsigned short* __restrict__ heads)
{
  __shared__ __align__(16) unsigned short Kt[128][136]; // 34816 B
  __shared__ __align__(16) unsigned short Vt[128][132]; // 33792 B (sigma cols)
  __shared__ float invs[64];

  const int tid = threadIdx.x;
  const int wave = tid >> 6, lane = tid & 63;
  const int fr = lane & 15, fq = lane >> 4;
  const int fk = fq * 8;
  const int rt = (blockIdx.z == 0) ? (int)blockIdx.x : (31 - (int)blockIdx.x);
  const int row0 = rt * 64;
  const int hh = blockIdx.y, bi = blockIdx.z;
  const int bh = bi * NH + hh;
  const int r0 = row0 + wave * 16;
  const int wmax = r0 + 15;
  const int myrow = r0 + fr; // this lane's S^T q-row

  const unsigned short* qb = q + bh * SEQ * DH;
  const unsigned short* kb = k + bh * SEQ * DH;
  const unsigned short* vb = vT + bh * DH * SEQ;

  bf16x8 aq[4];
#pragma unroll
  for (int ks = 0; ks < 4; ++ks)
    aq[ks] = *(const bf16x8*)(qb + myrow * DH + ks * 32 + fk);

  const int nph = (rt + 2) >> 1; // 128-col phases covering [0, row0+64)
  float rs = 0.f;

  f32x4 pv[8];
  {
    f32x4 zero4 = {0.f, 0.f, 0.f, 0.f};
#pragma unroll
    for (int i = 0; i < 8; ++i) pv[i] = zero4;
  }

  unsigned short* bandRow =
      (unsigned short*)attn + (((size_t)bh * SEQ + myrow) * SEQ) * 2;

  // ---- single pass: QK^T -> exp -> band store (bf16) + rowsum + PV ----
  for (int ph = 0; ph < nph; ++ph) {
    const int c0 = ph * 128;
    __syncthreads();
#pragma unroll
    for (int j = 0; j < 8; ++j) { // stage K + V(sigma-remapped)
      int f = j * 256 + tid;
      int r = f >> 4, c = (f & 15) * 8;
      *(bf16x8*)&Kt[r][c] = *(const bf16x8*)(kb + (c0 + r) * DH + c);
      bf16x8 w = *(const bf16x8*)(vb + r * SEQ + c0 + c);
      int cb = c & ~31, within = c & 31;
      int s8 = (within >> 3) & 1, b0 = within >> 4;
      int col0 = cb + 16 * s8 + 4 * b0;
      bf16x4 lo = {w[0], w[1], w[2], w[3]};
      bf16x4 hi = {w[4], w[5], w[6], w[7]};
      *(bf16x4*)&Vt[r][col0] = lo;
      *(bf16x4*)&Vt[r][col0 + 8] = hi;
    }
    __syncthreads();
#pragma unroll
    for (int chunk = 0; chunk < 4; ++chunk) {
      union { unsigned int u[4]; bf16x8 v8; } pa;
#pragma unroll
      for (int h2 = 0; h2 < 2; ++h2) {
        const int half = chunk * 2 + h2;
        const int ch = c0 + half * 16;
        const bool live = (ch <= wmax);
        f32x4 s = {0.f, 0.f, 0.f, 0.f};
        if (live) {
#pragma unroll
          for (int ks = 0; ks < 4; ++ks) {
            bf16x8 bk = *(const bf16x8*)&Kt[half * 16 + fr][ks * 32 + fk];
            s = MFMA(bk, aq[ks], s); // swapped: S^T
          }
        }
        float p[4];
#pragma unroll
        for (int r = 0; r < 4; ++r) {
          int col = ch + fq * 4 + r;
          p[r] = (live && col <= myrow) ? __expf(s[r] * SCALE) : 0.f;
        }
        rs += (p[0] + p[1]) + (p[2] + p[3]);
        pa.u[h2 * 2] = cvtpk(p[0], p[1]);
        pa.u[h2 * 2 + 1] = cvtpk(p[2], p[3]);
        uint2 bw;
        bw.x = pa.u[h2 * 2];
        bw.y = pa.u[h2 * 2 + 1];
        *(uint2*)(bandRow + ch + fq * 4) = bw; // NOT nt: keep in L2 for epilogue
      }
      // PV: B-frag one b128 in matching sigma order
#pragma unroll
      for (int ni = 0; ni < 8; ++ni) {
        bf16x8 bv = *(const bf16x8*)&Vt[ni * 16 + fr][chunk * 32 + fq * 8];
        pv[ni] = MFMA(pa.v8, bv, pv[ni]);
      }
    }
  }

  // ---- rowsum reduce -> invs ----
  rs += __shfl_xor(rs, 16, 64);
  rs += __shfl_xor(rs, 32, 64);
  if (fq == 0) invs[wave * 16 + fr] = 1.0f / rs;
  __syncthreads(); // also drains band stores (vmcnt 0 before barrier)

  // ---- heads = pv * inv(row) ----
  float invr[4];
#pragma unroll
  for (int r = 0; r < 4; ++r) invr[r] = invs[wave * 16 + fq * 4 + r];
#pragma unroll
  for (int ni = 0; ni < 8; ++ni)
#pragma unroll
    for (int r = 0; r < 4; ++r) {
      int row = r0 + fq * 4 + r;
      int dh = ni * 16 + fr;
      heads[(bi * SEQ + row) * DIM + hh * DH + dh] = f2bf(pv[ni][r] * invr[r]);
    }

  // ---- epilogue: in-place band normalize + expand bf16 -> f32 ----
  // 4 threads/row; 512-col quarters processed DESCENDING (f32 write to col c
  // clobbers bf16 cols 2c,2c+1 -> always in already-consumed regions);
  // vmcnt(0) fence between each quarter's loads and stores.
  {
    const int erow = row0 + (tid >> 2);
    const float rinv = invs[tid >> 2];
    const int sub = (tid & 3) * 128;
    const int W = nph * 128;
    unsigned short* brow =
        (unsigned short*)attn + (((size_t)bh * SEQ + erow) * SEQ) * 2;
    float* frow = attn + ((size_t)bh * SEQ + erow) * SEQ;
#pragma unroll
    for (int qd = 3; qd >= 0; --qd) {
      const int base = qd * 512 + sub;
      const bool in = (base < W); // base, W multiples of 128
      bf16x8 buf[16];
      if (in) {
#pragma unroll
        for (int i = 0; i < 16; ++i)
          buf[i] = *(const bf16x8*)&brow[base + i * 8];
      }
      asm volatile("s_waitcnt vmcnt(0)" ::: "memory");
#pragma unroll
      for (int i = 0; i < 16; ++i) {
        f32x4 w0 = {0.f, 0.f, 0.f, 0.f}, w1 = {0.f, 0.f, 0.f, 0.f};
        if (in) {
          w0[0] = bf2f((unsigned short)buf[i][0]) * rinv;
          w0[1] = bf2f((unsigned short)buf[i][1]) * rinv;
          w0[2] = bf2f((unsigned short)buf[i][2]) * rinv;
          w0[3] = bf2f((unsigned short)buf[i][3]) * rinv;
          w1[0] = bf2f((unsigned short)buf[i][4]) * rinv;
          w1[1] = bf2f((unsigned short)buf[i][5]) * rinv;
          w1[2] = bf2f((unsigned short)buf[i][6]) * rinv;
          w1[3] = bf2f((unsigned short)buf[i][7]) * rinv;
        }
        __builtin_nontemporal_store(w0, (f32x4*)(frow + base + i * 8));
        __builtin_nontemporal_store(w1, (f32x4*)(frow + base + i * 8 + 4));
      }
    }
  }
}

// ---------------------------------------------------------------------------
// K3: out = heads @ w_out^T  (M=4096, N=1024, K=1024), f32 output
// (round-4 form)
// ---------------------------------------------------------------------------
__global__ __launch_bounds__(256) void k_outproj(
    const unsigned short* __restrict__ heads, const float* __restrict__ wout,
    float* __restrict__ out)
{
  __shared__ __align__(16) unsigned short As[128][40];
  __shared__ __align__(16) unsigned short Bs[128][40];
  const int tid = threadIdx.x;
  const int wave = tid >> 6, lane = tid & 63;
  const int fr = lane & 15, fq = lane >> 4;
  const int fk = fq * 8;
  const int wr = (wave >> 1) * 64, wc = (wave & 1) * 64;
  const int m0 = blockIdx.x * 128, n0 = blockIdx.y * 128;

  f32x4 zero4 = {0.f, 0.f, 0.f, 0.f};
  f32x4 acc[4][4];
  for (int i = 0; i < 4; ++i)
    for (int j = 0; j < 4; ++j) acc[i][j] = zero4;

  for (int kt = 0; kt < 32; ++kt) {
    const int k0 = kt * 32;
    __syncthreads();
#pragma unroll
    for (int j = 0; j < 2; ++j) { // A tile: 128x32 bf16
      int f = j * 256 + tid;
      int row = f >> 2, c = (f & 3) * 8;
      *(bf16x8*)&As[row][c] = *(const bf16x8*)(heads + (m0 + row) * 1024 + k0 + c);
    }
#pragma unroll
    for (int j = 0; j < 4; ++j) { // B tile: 128x32 f32 -> bf16 via cvt_pk
      int f = j * 256 + tid;
      int row = f >> 3, c4 = (f & 7) * 4;
      f32x4 vb = *(const f32x4*)(wout + (n0 + row) * 1024 + k0 + c4);
      uint2 ub;
      ub.x = cvtpk(vb[0], vb[1]); ub.y = cvtpk(vb[2], vb[3]);
      *(uint2*)&Bs[row][c4] = ub;
    }
    __syncthreads();
    bf16x8 af[4], bfr[4];
#pragma unroll
    for (int mi = 0; mi < 4; ++mi) af[mi] = *(const bf16x8*)&As[wr + mi * 16 + fr][fk];
#pragma unroll
    for (int ni = 0; ni < 4; ++ni) bfr[ni] = *(const bf16x8*)&Bs[wc + ni * 16 + fr][fk];
#pragma unroll
    for (int mi = 0; mi < 4; ++mi)
#pragma unroll
      for (int ni = 0; ni < 4; ++ni)
        acc[mi][ni] = MFMA(af[mi], bfr[ni], acc[mi][ni]);
  }

#pragma unroll
  for (int mi = 0; mi < 4; ++mi)
#pragma unroll
    for (int ni = 0; ni < 4; ++ni)
#pragma unroll
      for (int r = 0; r < 4; ++r) {
        int m = m0 + wr + mi * 16 + fq * 4 + r;
        int n = n0 + wc + ni * 16 + fr;
        out[m * 1024 + n] = acc[mi][ni][r];
      }
}

extern "C" void kernel_launch(void* const* d_in, const int* in_sizes, int n_in,
                              void* d_out, int out_size, void* d_ws, size_t ws_size,
                              hipStream_t stream)
{
  const float* x    = (const float*)d_in[0];
  const float* wqkv = (const float*)d_in[1];
  const float* wout = (const float*)d_in[2];
  const float* cosT = (const float*)d_in[3];
  const float* sinT = (const float*)d_in[4];

  float* out  = (float*)d_out;
  float* attn = out + 4194304;
  unsigned short* ws = (unsigned short*)d_ws;
  unsigned short* q     = ws;             // (B,H,T,DH) bf16
  unsigned short* kk    = ws + 4194304;   // (B,H,T,DH) bf16
  unsigned short* vT    = ws + 8388608;   // (B,H,DH,T) bf16
  unsigned short* heads = ws + 12582912;  // (B,T,DIM) bf16

  k_qkv_rope<<<dim3(32, 24), 256, 0, stream>>>(x, wqkv, cosT, sinT, q, kk, vT);
  k_attn<<<dim3(32, 8, 2), 256, 0, stream>>>(q, kk, vT, attn, heads);
  k_outproj<<<dim3(32, 8), 256, 0, stream>>>(heads, wout, out);
}

// Round 16
// 226.988 us; speedup vs baseline: 3.3312x; 3.3312x over previous
//
#include <hip/hip_runtime.h>

typedef __attribute__((ext_vector_type(8))) short bf16x8;
typedef __attribute__((ext_vector_type(4))) short bf16x4;
typedef __attribute__((ext_vector_type(4))) float f32x4;

#define MFMA(a, b, c) __builtin_amdgcn_mfma_f32_16x16x32_bf16((a), (b), (c), 0, 0, 0)

__device__ __forceinline__ unsigned short f2bf(float f) {
  unsigned int x = __float_as_uint(f);
  return (unsigned short)((x + 0x7fffu + ((x >> 16) & 1u)) >> 16);
}
__device__ __forceinline__ unsigned int cvtpk(float lo, float hi) {
  unsigned int r;
  asm("v_cvt_pk_bf16_f32 %0, %1, %2" : "=v"(r) : "v"(lo), "v"(hi));
  return r;
}

constexpr int SEQ = 2048;
constexpr int NH = 8;
constexpr int DH = 128;
constexpr int DIM = 1024;
constexpr float SCALE = 0.08838834764831845f; // 1/sqrt(128)

// ---------------------------------------------------------------------------
// K1: qkv = x @ qkv_proj^T  (M=4096, N=3072, K=1024), fused RoPE epilogue.
// a = n0>>10 is block-uniform: q/k blocks keep the shfl-RoPE scalar path;
// v blocks transpose 64x64 wave tiles through LDS (aliasing dead As/Bs)
// and store vT as 128B-contiguous runs along t (was 2B scatters @4KB stride).
// ---------------------------------------------------------------------------
__global__ __launch_bounds__(256) void k_qkv_rope(
    const float* __restrict__ x, const float* __restrict__ wqkv,
    const float* __restrict__ cosT, const float* __restrict__ sinT,
    unsigned short* __restrict__ q, unsigned short* __restrict__ k,
    unsigned short* __restrict__ vT)
{
  __shared__ __align__(16) char smem1[39936]; // As(10240) + Bs(10240); epilogue: v-scratch 4x64x78x2
  unsigned short (*As)[40] = (unsigned short(*)[40])smem1;
  unsigned short (*Bs)[40] = (unsigned short(*)[40])(smem1 + 10240);

  const int tid = threadIdx.x;
  const int wave = tid >> 6, lane = tid & 63;
  const int fr = lane & 15, fq = lane >> 4;
  const int fk = fq * 8;
  const int wr = (wave >> 1) * 64, wc = (wave & 1) * 64;
  const int m0 = blockIdx.x * 128, n0 = blockIdx.y * 128;

  f32x4 zero4 = {0.f, 0.f, 0.f, 0.f};
  f32x4 acc[4][4];
  for (int i = 0; i < 4; ++i)
    for (int j = 0; j < 4; ++j) acc[i][j] = zero4;

  for (int kt = 0; kt < 32; ++kt) {
    const int k0 = kt * 32;
    __syncthreads();
#pragma unroll
    for (int j = 0; j < 4; ++j) {
      int f = j * 256 + tid;
      int row = f >> 3, c4 = (f & 7) * 4;
      f32x4 va = *(const f32x4*)(x + (m0 + row) * 1024 + k0 + c4);
      f32x4 vb = *(const f32x4*)(wqkv + (n0 + row) * 1024 + k0 + c4);
      uint2 ua, ub;
      ua.x = cvtpk(va[0], va[1]); ua.y = cvtpk(va[2], va[3]);
      ub.x = cvtpk(vb[0], vb[1]); ub.y = cvtpk(vb[2], vb[3]);
      *(uint2*)&As[row][c4] = ua;
      *(uint2*)&Bs[row][c4] = ub;
    }
    __syncthreads();
    bf16x8 af[4], bfr[4];
#pragma unroll
    for (int mi = 0; mi < 4; ++mi) af[mi] = *(const bf16x8*)&As[wr + mi * 16 + fr][fk];
#pragma unroll
    for (int ni = 0; ni < 4; ++ni) bfr[ni] = *(const bf16x8*)&Bs[wc + ni * 16 + fr][fk];
#pragma unroll
    for (int mi = 0; mi < 4; ++mi)
#pragma unroll
      for (int ni = 0; ni < 4; ++ni)
        acc[mi][ni] = MFMA(af[mi], bfr[ni], acc[mi][ni]);
  }

  if (n0 >= 2048) {
    // ---- v path: LDS transpose -> coalesced vT stores ----
    __syncthreads(); // As/Bs dead for ALL waves before aliasing
    unsigned short* scr = (unsigned short*)smem1 + wave * (64 * 78);
    const int hh = (n0 & 1023) >> 7;
    const int bi2 = (m0 + wr) >> 11;
    const int t0 = (m0 + wr) & 2047;
#pragma unroll
    for (int ni = 0; ni < 4; ++ni)
#pragma unroll
      for (int mi = 0; mi < 4; ++mi) {
        bf16x4 pk;
#pragma unroll
        for (int r = 0; r < 4; ++r) pk[r] = (short)f2bf(acc[mi][ni][r]);
        // [dh_local][t_local], pitch 78
        *(bf16x4*)&scr[(ni * 16 + fr) * 78 + mi * 16 + fq * 4] = pk;
      }
    // same-wave readback: 8 dh-rows x 128B contiguous per iteration
    const int a8 = lane >> 3, b8 = lane & 7;
#pragma unroll
    for (int c = 0; c < 8; ++c) {
      int dhl = c * 8 + a8;
      bf16x8 w = *(const bf16x8*)&scr[dhl * 78 + b8 * 8];
      *(bf16x8*)(vT + ((size_t)(bi2 * NH + hh) * DH + wc + dhl) * SEQ + t0 + b8 * 8) = w;
    }
  } else {
    // ---- q/k path: RoPE via shfl_xor(1), scalar stores (32B/row sectors) ----
    unsigned short* dst = (n0 >> 10) == 0 ? q : k;
#pragma unroll
    for (int mi = 0; mi < 4; ++mi)
#pragma unroll
      for (int ni = 0; ni < 4; ++ni)
#pragma unroll
        for (int r = 0; r < 4; ++r) {
          float val = acc[mi][ni][r];
          float other = __shfl_xor(val, 1, 64);
          int m = m0 + wr + mi * 16 + fq * 4 + r;
          int n = n0 + wc + ni * 16 + fr;
          int feat = n & 1023;
          int hh = feat >> 7, dh = feat & 127;
          int bi = m >> 11, t = m & 2047;
          float c = cosT[t * 64 + (dh >> 1)];
          float s = sinT[t * 64 + (dh >> 1)];
          float o = ((dh & 1) == 0) ? (val * c - other * s) : (other * s + val * c);
          dst[((bi * NH + hh) * SEQ + t) * DH + dh] = f2bf(o);
        }
  }
}

// ---------------------------------------------------------------------------
// K2: causal attention (r14, best measured): 256 thr, 4 waves x 16 rows,
// 128-col phases, swapped QK^T (S^T per lane), f32x4 nt attn stores,
// in-register P packing (cvt_pk, sigma k-order), sigma-remapped V staging.
// ---------------------------------------------------------------------------
__global__ __launch_bounds__(256) void k_attn(
    const unsigned short* __restrict__ q, const unsigned short* __restrict__ k,
    const unsigned short* __restrict__ vT,
    float* __restrict__ attn, unsigned short* __restrict__ heads)
{
  __shared__ __align__(16) unsigned short Kt[128][136]; // 34816 B
  __shared__ __align__(16) unsigned short Vt[128][132]; // 33792 B (sigma cols)

  const int tid = threadIdx.x;
  const int wave = tid >> 6, lane = tid & 63;
  const int fr = lane & 15, fq = lane >> 4;
  const int fk = fq * 8;
  const int rt = (blockIdx.z == 0) ? (int)blockIdx.x : (31 - (int)blockIdx.x);
  const int row0 = rt * 64;
  const int hh = blockIdx.y, bi = blockIdx.z;
  const int bh = bi * NH + hh;
  const int r0 = row0 + wave * 16;
  const int wmax = r0 + 15;
  const int myrow = r0 + fr; // this lane's S^T q-row

  const unsigned short* qb = q + bh * SEQ * DH;
  const unsigned short* kb = k + bh * SEQ * DH;
  const unsigned short* vb = vT + bh * DH * SEQ;

  bf16x8 aq[4];
#pragma unroll
  for (int ks = 0; ks < 4; ++ks)
    aq[ks] = *(const bf16x8*)(qb + myrow * DH + ks * 32 + fk);

  const int nph = (rt + 2) >> 1; // 128-col phases covering cols [0, row0+64)
  float rs = 0.f;

  // ---- pass A: row sums ----
  for (int ph = 0; ph < nph; ++ph) {
    const int c0 = ph * 128;
    __syncthreads();
#pragma unroll
    for (int j = 0; j < 8; ++j) { // stage K: 128 rows x 128 feats
      int f = j * 256 + tid;
      int r = f >> 4, c = (f & 15) * 8;
      *(bf16x8*)&Kt[r][c] = *(const bf16x8*)(kb + (c0 + r) * DH + c);
    }
    __syncthreads();
#pragma unroll
    for (int half = 0; half < 8; ++half) {
      int ch = c0 + half * 16;
      if (ch <= wmax) {
        f32x4 s = {0.f, 0.f, 0.f, 0.f};
#pragma unroll
        for (int ks = 0; ks < 4; ++ks) {
          bf16x8 bk = *(const bf16x8*)&Kt[half * 16 + fr][ks * 32 + fk];
          s = MFMA(bk, aq[ks], s); // swapped: S^T
        }
#pragma unroll
        for (int r = 0; r < 4; ++r) {
          int col = ch + fq * 4 + r;
          if (col <= myrow) rs += __expf(s[r] * SCALE);
        }
      }
    }
  }

  rs += __shfl_xor(rs, 16, 64);
  rs += __shfl_xor(rs, 32, 64);
  const float inv = 1.0f / rs;

  f32x4 pv[8];
  {
    f32x4 zero4 = {0.f, 0.f, 0.f, 0.f};
#pragma unroll
    for (int i = 0; i < 8; ++i) pv[i] = zero4;
  }

  // ---- pass B: f32 attn (vector nt stores) + PV ----
  for (int ph = 0; ph < nph; ++ph) {
    const int c0 = ph * 128;
    __syncthreads();
#pragma unroll
    for (int j = 0; j < 8; ++j) { // stage K + V(remapped)
      int f = j * 256 + tid;
      int r = f >> 4, c = (f & 15) * 8;
      *(bf16x8*)&Kt[r][c] = *(const bf16x8*)(kb + (c0 + r) * DH + c);
      bf16x8 w = *(const bf16x8*)(vb + r * SEQ + c0 + c);
      // sigma remap: t=16b+4q+rr -> t'=8q+4b+rr (within each 32-col group)
      int cb = c & ~31, within = c & 31;
      int s8 = (within >> 3) & 1, b0 = within >> 4;
      int col0 = cb + 16 * s8 + 4 * b0;
      bf16x4 lo = {w[0], w[1], w[2], w[3]};
      bf16x4 hi = {w[4], w[5], w[6], w[7]};
      *(bf16x4*)&Vt[r][col0] = lo;
      *(bf16x4*)&Vt[r][col0 + 8] = hi;
    }
    __syncthreads();
#pragma unroll
    for (int chunk = 0; chunk < 4; ++chunk) {
      union { unsigned int u[4]; bf16x8 v8; } pa;
#pragma unroll
      for (int h2 = 0; h2 < 2; ++h2) {
        const int half = chunk * 2 + h2;
        const int ch = c0 + half * 16;
        const bool live = (ch <= wmax);
        f32x4 s = {0.f, 0.f, 0.f, 0.f};
        if (live) {
#pragma unroll
          for (int ks = 0; ks < 4; ++ks) {
            bf16x8 bk = *(const bf16x8*)&Kt[half * 16 + fr][ks * 32 + fk];
            s = MFMA(bk, aq[ks], s); // swapped: S^T
          }
        }
        float p[4];
#pragma unroll
        for (int r = 0; r < 4; ++r) {
          int col = ch + fq * 4 + r;
          p[r] = (live && col <= myrow) ? __expf(s[r] * SCALE) * inv : 0.f;
        }
        f32x4 p4 = {p[0], p[1], p[2], p[3]};
        __builtin_nontemporal_store(
            p4, (f32x4*)(attn + ((size_t)bh * SEQ + myrow) * SEQ + ch + fq * 4));
        pa.u[h2 * 2] = cvtpk(p[0], p[1]);
        pa.u[h2 * 2 + 1] = cvtpk(p[2], p[3]);
      }
      // PV: B-frag is one b128 in matching sigma order
#pragma unroll
      for (int ni = 0; ni < 8; ++ni) {
        bf16x8 bv = *(const bf16x8*)&Vt[ni * 16 + fr][chunk * 32 + fq * 8];
        pv[ni] = MFMA(pa.v8, bv, pv[ni]);
      }
    }
  }

#pragma unroll
  for (int ni = 0; ni < 8; ++ni)
#pragma unroll
    for (int r = 0; r < 4; ++r) {
      int row = r0 + fq * 4 + r;
      int dh = ni * 16 + fr;
      heads[(bi * SEQ + row) * DIM + hh * DH + dh] = f2bf(pv[ni][r]);
    }

  // ---- tail: zero cols [nph*128, 2048), non-temporal ----
  {
    const int zstart = nph * 128;
    f32x4 z4 = {0.f, 0.f, 0.f, 0.f};
#pragma unroll
    for (int rr = 0; rr < 4; ++rr) {
      int row = r0 + rr * 4 + fq;
      float* dst = attn + ((size_t)bh * SEQ + row) * SEQ;
      for (int c = zstart + fr * 4; c < SEQ; c += 64)
        __builtin_nontemporal_store(z4, (f32x4*)(dst + c));
    }
  }
}

// ---------------------------------------------------------------------------
// K3: out = heads @ w_out^T  (M=4096, N=1024, K=1024), f32 output
// (round-4 form)
// ---------------------------------------------------------------------------
__global__ __launch_bounds__(256) void k_outproj(
    const unsigned short* __restrict__ heads, const float* __restrict__ wout,
    float* __restrict__ out)
{
  __shared__ __align__(16) unsigned short As[128][40];
  __shared__ __align__(16) unsigned short Bs[128][40];
  const int tid = threadIdx.x;
  const int wave = tid >> 6, lane = tid & 63;
  const int fr = lane & 15, fq = lane >> 4;
  const int fk = fq * 8;
  const int wr = (wave >> 1) * 64, wc = (wave & 1) * 64;
  const int m0 = blockIdx.x * 128, n0 = blockIdx.y * 128;

  f32x4 zero4 = {0.f, 0.f, 0.f, 0.f};
  f32x4 acc[4][4];
  for (int i = 0; i < 4; ++i)
    for (int j = 0; j < 4; ++j) acc[i][j] = zero4;

  for (int kt = 0; kt < 32; ++kt) {
    const int k0 = kt * 32;
    __syncthreads();
#pragma unroll
    for (int j = 0; j < 2; ++j) { // A tile: 128x32 bf16
      int f = j * 256 + tid;
      int row = f >> 2, c = (f & 3) * 8;
      *(bf16x8*)&As[row][c] = *(const bf16x8*)(heads + (m0 + row) * 1024 + k0 + c);
    }
#pragma unroll
    for (int j = 0; j < 4; ++j) { // B tile: 128x32 f32 -> bf16 via cvt_pk
      int f = j * 256 + tid;
      int row = f >> 3, c4 = (f & 7) * 4;
      f32x4 vb = *(const f32x4*)(wout + (n0 + row) * 1024 + k0 + c4);
      uint2 ub;
      ub.x = cvtpk(vb[0], vb[1]); ub.y = cvtpk(vb[2], vb[3]);
      *(uint2*)&Bs[row][c4] = ub;
    }
    __syncthreads();
    bf16x8 af[4], bfr[4];
#pragma unroll
    for (int mi = 0; mi < 4; ++mi) af[mi] = *(const bf16x8*)&As[wr + mi * 16 + fr][fk];
#pragma unroll
    for (int ni = 0; ni < 4; ++ni) bfr[ni] = *(const bf16x8*)&Bs[wc + ni * 16 + fr][fk];
#pragma unroll
    for (int mi = 0; mi < 4; ++mi)
#pragma unroll
      for (int ni = 0; ni < 4; ++ni)
        acc[mi][ni] = MFMA(af[mi], bfr[ni], acc[mi][ni]);
  }

#pragma unroll
  for (int mi = 0; mi < 4; ++mi)
#pragma unroll
    for (int ni = 0; ni < 4; ++ni)
#pragma unroll
      for (int r = 0; r < 4; ++r) {
        int m = m0 + wr + mi * 16 + fq * 4 + r;
        int n = n0 + wc + ni * 16 + fr;
        out[m * 1024 + n] = acc[mi][ni][r];
      }
}

extern "C" void kernel_launch(void* const* d_in, const int* in_sizes, int n_in,
                              void* d_out, int out_size, void* d_ws, size_t ws_size,
                              hipStream_t stream)
{
  const float* x    = (const float*)d_in[0];
  const float* wqkv = (const float*)d_in[1];
  const float* wout = (const float*)d_in[2];
  const float* cosT = (const float*)d_in[3];
  const float* sinT = (const float*)d_in[4];

  float* out  = (float*)d_out;
  float* attn = out + 4194304;
  unsigned short* ws = (unsigned short*)d_ws;
  unsigned short* q     = ws;             // (B,H,T,DH) bf16
  unsigned short* kk    = ws + 4194304;   // (B,H,T,DH) bf16
  unsigned short* vT    = ws + 8388608;   // (B,H,DH,T) bf16
  unsigned short* heads = ws + 12582912;  // (B,T,DIM) bf16

  k_qkv_rope<<<dim3(32, 24), 256, 0, stream>>>(x, wqkv, cosT, sinT, q, kk, vT);
  k_attn<<<dim3(32, 8, 2), 256, 0, stream>>>(q, kk, vT, attn, heads);
  k_outproj<<<dim3(32, 8), 256, 0, stream>>>(heads, wout, out);
}

// Round 17
// 205.650 us; speedup vs baseline: 3.6768x; 1.1038x over previous
//
#include <hip/hip_runtime.h>

typedef __attribute__((ext_vector_type(8))) short bf16x8;
typedef __attribute__((ext_vector_type(4))) short bf16x4;
typedef __attribute__((ext_vector_type(4))) float f32x4;

#define MFMA(a, b, c) __builtin_amdgcn_mfma_f32_16x16x32_bf16((a), (b), (c), 0, 0, 0)

__device__ __forceinline__ unsigned short f2bf(float f) {
  unsigned int x = __float_as_uint(f);
  return (unsigned short)((x + 0x7fffu + ((x >> 16) & 1u)) >> 16);
}
__device__ __forceinline__ unsigned int cvtpk(float lo, float hi) {
  unsigned int r;
  asm("v_cvt_pk_bf16_f32 %0, %1, %2" : "=v"(r) : "v"(lo), "v"(hi));
  return r;
}

constexpr int SEQ = 2048;
constexpr int NH = 8;
constexpr int DH = 128;
constexpr int DIM = 1024;
constexpr float SCALE = 0.08838834764831845f; // 1/sqrt(128)

// ---------------------------------------------------------------------------
// K1: qkv = x @ qkv_proj^T  (M=4096, N=3072, K=1024), fused RoPE epilogue.
// (exact round-4 form — best measured; vT 2B scatters are L2/L3-absorbed)
// ---------------------------------------------------------------------------
__global__ __launch_bounds__(256) void k_qkv_rope(
    const float* __restrict__ x, const float* __restrict__ wqkv,
    const float* __restrict__ cosT, const float* __restrict__ sinT,
    unsigned short* __restrict__ q, unsigned short* __restrict__ k,
    unsigned short* __restrict__ vT)
{
  __shared__ __align__(16) unsigned short As[128][40];
  __shared__ __align__(16) unsigned short Bs[128][40];
  const int tid = threadIdx.x;
  const int wave = tid >> 6, lane = tid & 63;
  const int fr = lane & 15, fq = lane >> 4;
  const int fk = fq * 8;
  const int wr = (wave >> 1) * 64, wc = (wave & 1) * 64;
  const int m0 = blockIdx.x * 128, n0 = blockIdx.y * 128;

  f32x4 zero4 = {0.f, 0.f, 0.f, 0.f};
  f32x4 acc[4][4];
  for (int i = 0; i < 4; ++i)
    for (int j = 0; j < 4; ++j) acc[i][j] = zero4;

  for (int kt = 0; kt < 32; ++kt) {
    const int k0 = kt * 32;
    __syncthreads();
#pragma unroll
    for (int j = 0; j < 4; ++j) {
      int f = j * 256 + tid;
      int row = f >> 3, c4 = (f & 7) * 4;
      f32x4 va = *(const f32x4*)(x + (m0 + row) * 1024 + k0 + c4);
      f32x4 vb = *(const f32x4*)(wqkv + (n0 + row) * 1024 + k0 + c4);
      uint2 ua, ub;
      ua.x = cvtpk(va[0], va[1]); ua.y = cvtpk(va[2], va[3]);
      ub.x = cvtpk(vb[0], vb[1]); ub.y = cvtpk(vb[2], vb[3]);
      *(uint2*)&As[row][c4] = ua;
      *(uint2*)&Bs[row][c4] = ub;
    }
    __syncthreads();
    bf16x8 af[4], bfr[4];
#pragma unroll
    for (int mi = 0; mi < 4; ++mi) af[mi] = *(const bf16x8*)&As[wr + mi * 16 + fr][fk];
#pragma unroll
    for (int ni = 0; ni < 4; ++ni) bfr[ni] = *(const bf16x8*)&Bs[wc + ni * 16 + fr][fk];
#pragma unroll
    for (int mi = 0; mi < 4; ++mi)
#pragma unroll
      for (int ni = 0; ni < 4; ++ni)
        acc[mi][ni] = MFMA(af[mi], bfr[ni], acc[mi][ni]);
  }

#pragma unroll
  for (int mi = 0; mi < 4; ++mi)
#pragma unroll
    for (int ni = 0; ni < 4; ++ni)
#pragma unroll
      for (int r = 0; r < 4; ++r) {
        float val = acc[mi][ni][r];
        float other = __shfl_xor(val, 1, 64);
        int m = m0 + wr + mi * 16 + fq * 4 + r;
        int n = n0 + wc + ni * 16 + fr;
        int a = n >> 10, feat = n & 1023;
        int hh = feat >> 7, dh = feat & 127;
        int bi = m >> 11, t = m & 2047;
        if (a == 2) {
          vT[((bi * NH + hh) * DH + dh) * SEQ + t] = f2bf(val);
        } else {
          float c = cosT[t * 64 + (dh >> 1)];
          float s = sinT[t * 64 + (dh >> 1)];
          float o = ((dh & 1) == 0) ? (val * c - other * s) : (other * s + val * c);
          unsigned short* dst = (a == 0) ? q : k;
          dst[((bi * NH + hh) * SEQ + t) * DH + dh] = f2bf(o);
        }
      }
}

// ---------------------------------------------------------------------------
// K2: causal attention (r14 exact, best measured): 256 thr, 4 waves x 16
// rows, 128-col phases, swapped QK^T (S^T per lane), f32x4 nt attn stores,
// in-register P packing (cvt_pk, sigma k-order), sigma-remapped V staging.
// ---------------------------------------------------------------------------
__global__ __launch_bounds__(256) void k_attn(
    const unsigned short* __restrict__ q, const unsigned short* __restrict__ k,
    const unsigned short* __restrict__ vT,
    float* __restrict__ attn, unsigned short* __restrict__ heads)
{
  __shared__ __align__(16) unsigned short Kt[128][136]; // 34816 B
  __shared__ __align__(16) unsigned short Vt[128][132]; // 33792 B (sigma cols)

  const int tid = threadIdx.x;
  const int wave = tid >> 6, lane = tid & 63;
  const int fr = lane & 15, fq = lane >> 4;
  const int fk = fq * 8;
  const int rt = (blockIdx.z == 0) ? (int)blockIdx.x : (31 - (int)blockIdx.x);
  const int row0 = rt * 64;
  const int hh = blockIdx.y, bi = blockIdx.z;
  const int bh = bi * NH + hh;
  const int r0 = row0 + wave * 16;
  const int wmax = r0 + 15;
  const int myrow = r0 + fr; // this lane's S^T q-row

  const unsigned short* qb = q + bh * SEQ * DH;
  const unsigned short* kb = k + bh * SEQ * DH;
  const unsigned short* vb = vT + bh * DH * SEQ;

  bf16x8 aq[4];
#pragma unroll
  for (int ks = 0; ks < 4; ++ks)
    aq[ks] = *(const bf16x8*)(qb + myrow * DH + ks * 32 + fk);

  const int nph = (rt + 2) >> 1; // 128-col phases covering cols [0, row0+64)
  float rs = 0.f;

  // ---- pass A: row sums ----
  for (int ph = 0; ph < nph; ++ph) {
    const int c0 = ph * 128;
    __syncthreads();
#pragma unroll
    for (int j = 0; j < 8; ++j) { // stage K: 128 rows x 128 feats
      int f = j * 256 + tid;
      int r = f >> 4, c = (f & 15) * 8;
      *(bf16x8*)&Kt[r][c] = *(const bf16x8*)(kb + (c0 + r) * DH + c);
    }
    __syncthreads();
#pragma unroll
    for (int half = 0; half < 8; ++half) {
      int ch = c0 + half * 16;
      if (ch <= wmax) {
        f32x4 s = {0.f, 0.f, 0.f, 0.f};
#pragma unroll
        for (int ks = 0; ks < 4; ++ks) {
          bf16x8 bk = *(const bf16x8*)&Kt[half * 16 + fr][ks * 32 + fk];
          s = MFMA(bk, aq[ks], s); // swapped: S^T
        }
#pragma unroll
        for (int r = 0; r < 4; ++r) {
          int col = ch + fq * 4 + r;
          if (col <= myrow) rs += __expf(s[r] * SCALE);
        }
      }
    }
  }

  rs += __shfl_xor(rs, 16, 64);
  rs += __shfl_xor(rs, 32, 64);
  const float inv = 1.0f / rs;

  f32x4 pv[8];
  {
    f32x4 zero4 = {0.f, 0.f, 0.f, 0.f};
#pragma unroll
    for (int i = 0; i < 8; ++i) pv[i] = zero4;
  }

  // ---- pass B: f32 attn (vector nt stores) + PV ----
  for (int ph = 0; ph < nph; ++ph) {
    const int c0 = ph * 128;
    __syncthreads();
#pragma unroll
    for (int j = 0; j < 8; ++j) { // stage K + V(remapped)
      int f = j * 256 + tid;
      int r = f >> 4, c = (f & 15) * 8;
      *(bf16x8*)&Kt[r][c] = *(const bf16x8*)(kb + (c0 + r) * DH + c);
      bf16x8 w = *(const bf16x8*)(vb + r * SEQ + c0 + c);
      // sigma remap: t=16b+4q+rr -> t'=8q+4b+rr (within each 32-col group)
      int cb = c & ~31, within = c & 31;
      int s8 = (within >> 3) & 1, b0 = within >> 4;
      int col0 = cb + 16 * s8 + 4 * b0;
      bf16x4 lo = {w[0], w[1], w[2], w[3]};
      bf16x4 hi = {w[4], w[5], w[6], w[7]};
      *(bf16x4*)&Vt[r][col0] = lo;
      *(bf16x4*)&Vt[r][col0 + 8] = hi;
    }
    __syncthreads();
#pragma unroll
    for (int chunk = 0; chunk < 4; ++chunk) {
      union { unsigned int u[4]; bf16x8 v8; } pa;
#pragma unroll
      for (int h2 = 0; h2 < 2; ++h2) {
        const int half = chunk * 2 + h2;
        const int ch = c0 + half * 16;
        const bool live = (ch <= wmax);
        f32x4 s = {0.f, 0.f, 0.f, 0.f};
        if (live) {
#pragma unroll
          for (int ks = 0; ks < 4; ++ks) {
            bf16x8 bk = *(const bf16x8*)&Kt[half * 16 + fr][ks * 32 + fk];
            s = MFMA(bk, aq[ks], s); // swapped: S^T
          }
        }
        float p[4];
#pragma unroll
        for (int r = 0; r < 4; ++r) {
          int col = ch + fq * 4 + r;
          p[r] = (live && col <= myrow) ? __expf(s[r] * SCALE) * inv : 0.f;
        }
        f32x4 p4 = {p[0], p[1], p[2], p[3]};
        __builtin_nontemporal_store(
            p4, (f32x4*)(attn + ((size_t)bh * SEQ + myrow) * SEQ + ch + fq * 4));
        pa.u[h2 * 2] = cvtpk(p[0], p[1]);
        pa.u[h2 * 2 + 1] = cvtpk(p[2], p[3]);
      }
      // PV: B-frag is one b128 in matching sigma order
#pragma unroll
      for (int ni = 0; ni < 8; ++ni) {
        bf16x8 bv = *(const bf16x8*)&Vt[ni * 16 + fr][chunk * 32 + fq * 8];
        pv[ni] = MFMA(pa.v8, bv, pv[ni]);
      }
    }
  }

#pragma unroll
  for (int ni = 0; ni < 8; ++ni)
#pragma unroll
    for (int r = 0; r < 4; ++r) {
      int row = r0 + fq * 4 + r;
      int dh = ni * 16 + fr;
      heads[(bi * SEQ + row) * DIM + hh * DH + dh] = f2bf(pv[ni][r]);
    }

  // ---- tail: zero cols [nph*128, 2048), non-temporal ----
  {
    const int zstart = nph * 128;
    f32x4 z4 = {0.f, 0.f, 0.f, 0.f};
#pragma unroll
    for (int rr = 0; rr < 4; ++rr) {
      int row = r0 + rr * 4 + fq;
      float* dst = attn + ((size_t)bh * SEQ + row) * SEQ;
      for (int c = zstart + fr * 4; c < SEQ; c += 64)
        __builtin_nontemporal_store(z4, (f32x4*)(dst + c));
    }
  }
}

// ---------------------------------------------------------------------------
// K3: out = heads @ w_out^T  (M=4096, N=1024, K=1024), f32 output.
// 64x128 tiles -> grid (64,8) = 512 blocks = 2 blocks/CU (was 1): the
// co-resident partner block overlaps staging drains with MFMA (m114).
// ---------------------------------------------------------------------------
__global__ __launch_bounds__(256) void k_outproj(
    const unsigned short* __restrict__ heads, const float* __restrict__ wout,
    float* __restrict__ out)
{
  __shared__ __align__(16) unsigned short As[64][40];   // 5120 B
  __shared__ __align__(16) unsigned short Bs[128][40];  // 10240 B
  const int tid = threadIdx.x;
  const int wave = tid >> 6, lane = tid & 63;
  const int fr = lane & 15, fq = lane >> 4;
  const int fk = fq * 8;
  const int wr = (wave >> 1) * 32, wc = (wave & 1) * 64;
  const int m0 = blockIdx.x * 64, n0 = blockIdx.y * 128;

  f32x4 zero4 = {0.f, 0.f, 0.f, 0.f};
  f32x4 acc[2][4];
  for (int i = 0; i < 2; ++i)
    for (int j = 0; j < 4; ++j) acc[i][j] = zero4;

  for (int kt = 0; kt < 32; ++kt) {
    const int k0 = kt * 32;
    __syncthreads();
    { // A tile: 64x32 bf16, one bf16x8 per thread
      int row = tid >> 2, c = (tid & 3) * 8;
      *(bf16x8*)&As[row][c] = *(const bf16x8*)(heads + (m0 + row) * 1024 + k0 + c);
    }
#pragma unroll
    for (int j = 0; j < 4; ++j) { // B tile: 128x32 f32 -> bf16 via cvt_pk
      int f = j * 256 + tid;
      int row = f >> 3, c4 = (f & 7) * 4;
      f32x4 vb = *(const f32x4*)(wout + (n0 + row) * 1024 + k0 + c4);
      uint2 ub;
      ub.x = cvtpk(vb[0], vb[1]); ub.y = cvtpk(vb[2], vb[3]);
      *(uint2*)&Bs[row][c4] = ub;
    }
    __syncthreads();
    bf16x8 af[2], bfr[4];
#pragma unroll
    for (int mi = 0; mi < 2; ++mi) af[mi] = *(const bf16x8*)&As[wr + mi * 16 + fr][fk];
#pragma unroll
    for (int ni = 0; ni < 4; ++ni) bfr[ni] = *(const bf16x8*)&Bs[wc + ni * 16 + fr][fk];
#pragma unroll
    for (int mi = 0; mi < 2; ++mi)
#pragma unroll
      for (int ni = 0; ni < 4; ++ni)
        acc[mi][ni] = MFMA(af[mi], bfr[ni], acc[mi][ni]);
  }

#pragma unroll
  for (int mi = 0; mi < 2; ++mi)
#pragma unroll
    for (int ni = 0; ni < 4; ++ni)
#pragma unroll
      for (int r = 0; r < 4; ++r) {
        int m = m0 + wr + mi * 16 + fq * 4 + r;
        int n = n0 + wc + ni * 16 + fr;
        out[m * 1024 + n] = acc[mi][ni][r];
      }
}

extern "C" void kernel_launch(void* const* d_in, const int* in_sizes, int n_in,
                              void* d_out, int out_size, void* d_ws, size_t ws_size,
                              hipStream_t stream)
{
  const float* x    = (const float*)d_in[0];
  const float* wqkv = (const float*)d_in[1];
  const float* wout = (const float*)d_in[2];
  const float* cosT = (const float*)d_in[3];
  const float* sinT = (const float*)d_in[4];

  float* out  = (float*)d_out;
  float* attn = out + 4194304;
  unsigned short* ws = (unsigned short*)d_ws;
  unsigned short* q     = ws;             // (B,H,T,DH) bf16
  unsigned short* kk    = ws + 4194304;   // (B,H,T,DH) bf16
  unsigned short* vT    = ws + 8388608;   // (B,H,DH,T) bf16
  unsigned short* heads = ws + 12582912;  // (B,T,DIM) bf16

  k_qkv_rope<<<dim3(32, 24), 256, 0, stream>>>(x, wqkv, cosT, sinT, q, kk, vT);
  k_attn<<<dim3(32, 8, 2), 256, 0, stream>>>(q, kk, vT, attn, heads);
  k_outproj<<<dim3(64, 8), 256, 0, stream>>>(heads, wout, out);
}